// Round 1
// baseline (1250.250 us; speedup 1.0000x reference)
//
#include <hip/hip_runtime.h>
#include <hip/hip_bf16.h>
#include <cstdint>
#include <cstddef>

#define N_NODES 50000
#define N_EDGES 600000
#define DF 128
#define N_ETYPES 4
#define N_STEPS 5

typedef _Float16 f16x8 __attribute__((ext_vector_type(8)));
typedef _Float16 f16x4 __attribute__((ext_vector_type(4)));
typedef _Float16 f16x2 __attribute__((ext_vector_type(2)));
typedef float f32x4 __attribute__((ext_vector_type(4)));

__device__ __forceinline__ float sigmoid_fast(float x) {
    return 1.0f / (1.0f + __expf(-x));
}
__device__ __forceinline__ float tanh_fast(float x) {
    // tanh(x) = 1 - 2/(e^{2x}+1); saturates correctly for |x| large
    return 1.0f - 2.0f / (__expf(2.0f * x) + 1.0f);
}

// ---------------- setup kernels (once per launch) ----------------

__global__ __launch_bounds__(256) void k_cvt_w(
    const float* __restrict__ Wl, const float* __restrict__ wih,
    const float* __restrict__ whh, _Float16* __restrict__ Wl_h,
    _Float16* __restrict__ wih_h, _Float16* __restrict__ whh_h) {
    int i = blockIdx.x * 256 + threadIdx.x;          // grid covers 65536
    if (i < N_ETYPES * DF * DF) Wl_h[i] = (_Float16)Wl[i];
    if (i < 3 * DF * DF) {
        wih_h[i] = (_Float16)wih[i];
        whh_h[i] = (_Float16)whh[i];
    }
}

__global__ __launch_bounds__(256) void k_cvt_h(
    const float* __restrict__ h, _Float16* __restrict__ hh, int n4) {
    int i = blockIdx.x * 256 + threadIdx.x;
    if (i < n4) {
        float4 v = ((const float4*)h)[i];
        f16x4 o;
        o.x = (_Float16)v.x; o.y = (_Float16)v.y;
        o.z = (_Float16)v.z; o.w = (_Float16)v.w;
        ((f16x4*)hh)[i] = o;
    }
}

__global__ __launch_bounds__(256) void k_hist(
    const int* __restrict__ dst, int* __restrict__ deg, int E) {
    int i = blockIdx.x * 256 + threadIdx.x;
    if (i < E) atomicAdd(&deg[dst[i]], 1);
}

__global__ __launch_bounds__(1024) void k_scan(
    const int* __restrict__ deg, int* __restrict__ row_start,
    int* __restrict__ cursor, int N) {
    __shared__ int sums[1024];
    int t = threadIdx.x;
    int chunk = (N + 1023) >> 10;                    // 49
    int beg = t * chunk;
    int end = beg + chunk; if (end > N) end = N; if (beg > N) beg = N;
    int s = 0;
    for (int i = beg; i < end; i++) s += deg[i];
    sums[t] = s;
    __syncthreads();
    for (int off = 1; off < 1024; off <<= 1) {
        int v = (t >= off) ? sums[t - off] : 0;
        __syncthreads();
        sums[t] += v;
        __syncthreads();
    }
    int base = sums[t] - s;                          // exclusive prefix
    for (int i = beg; i < end; i++) {
        row_start[i] = base;
        cursor[i] = base;
        base += deg[i];
    }
    if (t == 1023) row_start[N] = base;              // thread 1023's chunk is empty -> base = total
}

__global__ __launch_bounds__(256) void k_fill(
    const int* __restrict__ src, const int* __restrict__ dst,
    const int* __restrict__ ety, int* __restrict__ cursor,
    int* __restrict__ csr, int E) {
    int i = blockIdx.x * 256 + threadIdx.x;
    if (i < E) {
        int slot = atomicAdd(&cursor[dst[i]], 1);
        csr[slot] = src[i] | ((ety[i] - 1) << 16);   // src < 65536, et in 0..3
    }
}

// ---------------- per-step kernels ----------------

// t[k][n][f] = sum_d h[n,d] * W[k][f,d] + b_lin[k][f]   (f16 out, fp32 accum)
__global__ __launch_bounds__(256) void k_lin(
    const _Float16* __restrict__ hh, const _Float16* __restrict__ Wl,
    const float* __restrict__ b_lin, _Float16* __restrict__ t_out, int N) {
    const int wave = threadIdx.x >> 6, lane = threadIdx.x & 63;
    const int col = lane & 15, quad = lane >> 4;
    const int r0 = blockIdx.x * 64 + wave * 16;
    const int ktype = blockIdx.y;
    int arow = r0 + col; if (arow >= N) arow = N - 1;
    f16x8 a[4];
    const _Float16* hp = hh + (size_t)arow * DF + quad * 8;
#pragma unroll
    for (int kt = 0; kt < 4; kt++) a[kt] = *(const f16x8*)(hp + kt * 32);
    const _Float16* W = Wl + (size_t)ktype * DF * DF;
    _Float16* tk = t_out + (size_t)ktype * N * DF;
#pragma unroll
    for (int ft = 0; ft < 8; ft++) {
        f32x4 acc = {0.f, 0.f, 0.f, 0.f};
        const _Float16* wrow = W + (size_t)(ft * 16 + col) * DF + quad * 8;
#pragma unroll
        for (int kt = 0; kt < 4; kt++)
            acc = __builtin_amdgcn_mfma_f32_16x16x32_f16(
                a[kt], *(const f16x8*)(wrow + kt * 32), acc, 0, 0, 0);
        float bias = b_lin[ktype * DF + ft * 16 + col];
#pragma unroll
        for (int i = 0; i < 4; i++) {
            int row = r0 + quad * 4 + i;
            if (row < N)
                tk[(size_t)row * DF + ft * 16 + col] = (_Float16)(acc[i] + bias);
        }
    }
}

// a[n][:] = sum over incoming edges of t[et][src][:]  -> f16
__global__ __launch_bounds__(256) void k_agg(
    const _Float16* __restrict__ t, const int* __restrict__ row_start,
    const int* __restrict__ csr, _Float16* __restrict__ ah, int N) {
    const int wave = threadIdx.x >> 6, lane = threadIdx.x & 63;
    const int n = blockIdx.x * 4 + wave;             // grid = N/4 exactly
    const int beg = row_start[n], end = row_start[n + 1];
    float s0 = 0.f, s1 = 0.f, s2 = 0.f, s3 = 0.f;
    int e = beg;
    for (; e + 1 < end; e += 2) {
        int p0 = csr[e], p1 = csr[e + 1];
        f16x2 v0 = *(const f16x2*)(t + ((((size_t)(p0 >> 16)) * N + (p0 & 0xFFFF)) << 7) + lane * 2);
        f16x2 v1 = *(const f16x2*)(t + ((((size_t)(p1 >> 16)) * N + (p1 & 0xFFFF)) << 7) + lane * 2);
        s0 += (float)v0.x; s1 += (float)v0.y;
        s2 += (float)v1.x; s3 += (float)v1.y;
    }
    if (e < end) {
        int p0 = csr[e];
        f16x2 v0 = *(const f16x2*)(t + ((((size_t)(p0 >> 16)) * N + (p0 & 0xFFFF)) << 7) + lane * 2);
        s0 += (float)v0.x; s1 += (float)v0.y;
    }
    f16x2 o;
    o.x = (_Float16)(s0 + s2);
    o.y = (_Float16)(s1 + s3);
    *(f16x2*)(ah + ((size_t)n << 7) + lane * 2) = o;
}

// GRU: gi = a@wih.T + b_ih, gh = h@whh.T + b_hh, gates, h' -> fp32 + f16
// blockIdx.y = col-group (16 cols of the 128). h_in/h_out may alias (elementwise, per-lane RAW only).
__global__ __launch_bounds__(256) void k_gru(
    const _Float16* __restrict__ ah, const _Float16* __restrict__ hh,
    const _Float16* __restrict__ wih, const _Float16* __restrict__ whh,
    const float* __restrict__ b_ih, const float* __restrict__ b_hh,
    const float* h_in, float* h_out, _Float16* __restrict__ hh_next, int N) {
    const int wave = threadIdx.x >> 6, lane = threadIdx.x & 63;
    const int col = lane & 15, quad = lane >> 4;
    const int r0 = blockIdx.x * 64 + wave * 16;
    const int c0 = blockIdx.y * 16;
    int arow = r0 + col; if (arow >= N) arow = N - 1;
    f16x8 af[4], hf[4];
    const _Float16* ap = ah + (size_t)arow * DF + quad * 8;
    const _Float16* hp = hh + (size_t)arow * DF + quad * 8;
#pragma unroll
    for (int kt = 0; kt < 4; kt++) {
        af[kt] = *(const f16x8*)(ap + kt * 32);
        hf[kt] = *(const f16x8*)(hp + kt * 32);
    }
    f32x4 ir = {0.f,0.f,0.f,0.f}, iz = {0.f,0.f,0.f,0.f}, inn = {0.f,0.f,0.f,0.f};
    f32x4 hr = {0.f,0.f,0.f,0.f}, hz = {0.f,0.f,0.f,0.f}, hnn = {0.f,0.f,0.f,0.f};
    const _Float16* wr = wih + (size_t)(c0 + col) * DF + quad * 8;
    const _Float16* wz = wr + 128 * DF;
    const _Float16* wn = wr + 256 * DF;
    const _Float16* vr = whh + (size_t)(c0 + col) * DF + quad * 8;
    const _Float16* vz = vr + 128 * DF;
    const _Float16* vn = vr + 256 * DF;
#pragma unroll
    for (int kt = 0; kt < 4; kt++) {
        ir  = __builtin_amdgcn_mfma_f32_16x16x32_f16(af[kt], *(const f16x8*)(wr + kt * 32), ir,  0, 0, 0);
        iz  = __builtin_amdgcn_mfma_f32_16x16x32_f16(af[kt], *(const f16x8*)(wz + kt * 32), iz,  0, 0, 0);
        inn = __builtin_amdgcn_mfma_f32_16x16x32_f16(af[kt], *(const f16x8*)(wn + kt * 32), inn, 0, 0, 0);
        hr  = __builtin_amdgcn_mfma_f32_16x16x32_f16(hf[kt], *(const f16x8*)(vr + kt * 32), hr,  0, 0, 0);
        hz  = __builtin_amdgcn_mfma_f32_16x16x32_f16(hf[kt], *(const f16x8*)(vz + kt * 32), hz,  0, 0, 0);
        hnn = __builtin_amdgcn_mfma_f32_16x16x32_f16(hf[kt], *(const f16x8*)(vn + kt * 32), hnn, 0, 0, 0);
    }
    const float bir = b_ih[c0 + col], biz = b_ih[128 + c0 + col], bin = b_ih[256 + c0 + col];
    const float bhr = b_hh[c0 + col], bhz = b_hh[128 + c0 + col], bhn = b_hh[256 + c0 + col];
#pragma unroll
    for (int i = 0; i < 4; i++) {
        int row = r0 + quad * 4 + i;
        if (row < N) {
            float r = sigmoid_fast(ir[i] + bir + hr[i] + bhr);
            float z = sigmoid_fast(iz[i] + biz + hz[i] + bhz);
            float n = tanh_fast(inn[i] + bin + r * (hnn[i] + bhn));
            size_t idx = (size_t)row * DF + c0 + col;
            float hprev = h_in[idx];
            float hv = (1.f - z) * n + z * hprev;
            h_out[idx] = hv;
            hh_next[idx] = (_Float16)hv;
        }
    }
}

// ---------------- launch ----------------

extern "C" void kernel_launch(void* const* d_in, const int* in_sizes, int n_in,
                              void* d_out, int out_size, void* d_ws, size_t ws_size,
                              hipStream_t stream) {
    const float* h0    = (const float*)d_in[0];
    const int*   src   = (const int*)d_in[1];
    const int*   dst   = (const int*)d_in[2];
    const int*   ety   = (const int*)d_in[3];
    const float* W_lin = (const float*)d_in[4];
    const float* b_lin = (const float*)d_in[5];
    const float* w_ih  = (const float*)d_in[6];
    const float* w_hh  = (const float*)d_in[7];
    const float* b_ih  = (const float*)d_in[8];
    const float* b_hh  = (const float*)d_in[9];
    float* hout = (float*)d_out;

    char* p = (char*)d_ws;
    auto alloc = [&](size_t bytes) -> char* {
        char* r = p;
        p += (bytes + 255) & ~(size_t)255;
        return r;
    };
    _Float16* h_half_a = (_Float16*)alloc((size_t)N_NODES * DF * 2);
    _Float16* h_half_b = (_Float16*)alloc((size_t)N_NODES * DF * 2);
    _Float16* a_half   = (_Float16*)alloc((size_t)N_NODES * DF * 2);
    _Float16* t_half   = (_Float16*)alloc((size_t)N_ETYPES * N_NODES * DF * 2);
    _Float16* Wl_h     = (_Float16*)alloc((size_t)N_ETYPES * DF * DF * 2);
    _Float16* wih_h    = (_Float16*)alloc((size_t)3 * DF * DF * 2);
    _Float16* whh_h    = (_Float16*)alloc((size_t)3 * DF * DF * 2);
    int* deg       = (int*)alloc((size_t)N_NODES * 4);
    int* row_start = (int*)alloc((size_t)(N_NODES + 1) * 4);
    int* cursor    = (int*)alloc((size_t)N_NODES * 4);
    int* csr       = (int*)alloc((size_t)N_EDGES * 4);

    hipMemsetAsync(deg, 0, (size_t)N_NODES * 4, stream);
    k_cvt_w<<<256, 256, 0, stream>>>(W_lin, w_ih, w_hh, Wl_h, wih_h, whh_h);
    k_cvt_h<<<(N_NODES * DF / 4 + 255) / 256, 256, 0, stream>>>(h0, h_half_a, N_NODES * DF / 4);
    k_hist<<<(N_EDGES + 255) / 256, 256, 0, stream>>>(dst, deg, N_EDGES);
    k_scan<<<1, 1024, 0, stream>>>(deg, row_start, cursor, N_NODES);
    k_fill<<<(N_EDGES + 255) / 256, 256, 0, stream>>>(src, dst, ety, cursor, csr, N_EDGES);

    _Float16* hc = h_half_a;
    _Float16* hn = h_half_b;
    const int nb = (N_NODES + 63) / 64;              // 782
    for (int s = 0; s < N_STEPS; s++) {
        k_lin<<<dim3(nb, N_ETYPES), 256, 0, stream>>>(hc, Wl_h, b_lin, t_half, N_NODES);
        k_agg<<<N_NODES / 4, 256, 0, stream>>>(t_half, row_start, csr, a_half, N_NODES);
        const float* hin = (s == 0) ? h0 : hout;
        k_gru<<<dim3(nb, 8), 256, 0, stream>>>(a_half, hc, wih_h, whh_h, b_ih, b_hh,
                                               hin, hout, hn, N_NODES);
        _Float16* tmp = hc; hc = hn; hn = tmp;
    }
}

// Round 2
// 1109.253 us; speedup vs baseline: 1.1271x; 1.1271x over previous
//
#include <hip/hip_runtime.h>
#include <hip/hip_bf16.h>
#include <cstdint>
#include <cstddef>

#define N_NODES 50000
#define N_EDGES 600000
#define DF 128
#define N_ETYPES 4
#define N_STEPS 5
#define SCAN_NB 196   // ceil(50000/256)

typedef _Float16 f16x8 __attribute__((ext_vector_type(8)));
typedef _Float16 f16x4 __attribute__((ext_vector_type(4)));
typedef _Float16 f16x2 __attribute__((ext_vector_type(2)));
typedef float f32x4 __attribute__((ext_vector_type(4)));

__device__ __forceinline__ float sigmoid_fast(float x) {
    return 1.0f / (1.0f + __expf(-x));
}
__device__ __forceinline__ float tanh_fast(float x) {
    return 1.0f - 2.0f / (__expf(2.0f * x) + 1.0f);
}

// ---------------- setup kernels (once per launch) ----------------

__global__ __launch_bounds__(256) void k_cvt_w(
    const float* __restrict__ Wl, const float* __restrict__ wih,
    const float* __restrict__ whh, _Float16* __restrict__ Wl_h,
    _Float16* __restrict__ wih_h, _Float16* __restrict__ whh_h) {
    int i = blockIdx.x * 256 + threadIdx.x;          // grid covers 65536
    if (i < N_ETYPES * DF * DF) Wl_h[i] = (_Float16)Wl[i];
    if (i < 3 * DF * DF) {
        wih_h[i] = (_Float16)wih[i];
        whh_h[i] = (_Float16)whh[i];
    }
}

__global__ __launch_bounds__(256) void k_cvt_h(
    const float* __restrict__ h, _Float16* __restrict__ hh, int n4) {
    int i = blockIdx.x * 256 + threadIdx.x;
    if (i < n4) {
        float4 v = ((const float4*)h)[i];
        f16x4 o;
        o.x = (_Float16)v.x; o.y = (_Float16)v.y;
        o.z = (_Float16)v.z; o.w = (_Float16)v.w;
        ((f16x4*)hh)[i] = o;
    }
}

__global__ __launch_bounds__(256) void k_hist(
    const int* __restrict__ dst, int* __restrict__ deg, int E) {
    int i = blockIdx.x * 256 + threadIdx.x;
    if (i < E) atomicAdd(&deg[dst[i]], 1);
}

// hierarchical exclusive scan over deg[0..N): 3 small full-occupancy kernels
__global__ __launch_bounds__(256) void k_part(
    const int* __restrict__ deg, int* __restrict__ part, int N) {
    __shared__ int s[256];
    int t = threadIdx.x, i = blockIdx.x * 256 + t;
    s[t] = (i < N) ? deg[i] : 0;
    __syncthreads();
    for (int off = 128; off > 0; off >>= 1) {
        if (t < off) s[t] += s[t + off];
        __syncthreads();
    }
    if (t == 0) part[blockIdx.x] = s[0];
}

__global__ __launch_bounds__(256) void k_scan1(int* __restrict__ part, int nb) {
    __shared__ int s[256];
    int t = threadIdx.x;
    int v = (t < nb) ? part[t] : 0;
    s[t] = v;
    __syncthreads();
    for (int off = 1; off < 256; off <<= 1) {
        int u = (t >= off) ? s[t - off] : 0;
        __syncthreads();
        s[t] += u;
        __syncthreads();
    }
    if (t < nb) part[t] = s[t] - v;                  // exclusive prefix of block sums
}

__global__ __launch_bounds__(256) void k_row(
    const int* __restrict__ deg, const int* __restrict__ part,
    int* __restrict__ row_start, int* __restrict__ cursor, int N) {
    __shared__ int s[256];
    int t = threadIdx.x, i = blockIdx.x * 256 + t;
    int d = (i < N) ? deg[i] : 0;
    s[t] = d;
    __syncthreads();
    for (int off = 1; off < 256; off <<= 1) {
        int u = (t >= off) ? s[t - off] : 0;
        __syncthreads();
        s[t] += u;
        __syncthreads();
    }
    int rs = part[blockIdx.x] + s[t] - d;            // global exclusive prefix
    if (i < N) {
        row_start[i] = rs;
        cursor[i] = rs;
        if (i == N - 1) row_start[N] = rs + d;
    }
}

__global__ __launch_bounds__(256) void k_fill(
    const int* __restrict__ src, const int* __restrict__ dst,
    const int* __restrict__ ety, int* __restrict__ cursor,
    int* __restrict__ csr, int E) {
    int i = blockIdx.x * 256 + threadIdx.x;
    if (i < E) {
        int slot = atomicAdd(&cursor[dst[i]], 1);
        csr[slot] = src[i] | ((ety[i] - 1) << 16);   // src < 65536, et in 0..3
    }
}

// ---------------- per-step kernels ----------------

// t[k][n][f] = sum_d h[n,d] * W[k][f,d] + b_lin[k][f]   (f16 out, fp32 accum)
// All 4 etypes in one wave: A-fragments loaded once, reused 4x.
__global__ __launch_bounds__(256) void k_lin(
    const _Float16* __restrict__ hh, const _Float16* __restrict__ Wl,
    const float* __restrict__ b_lin, _Float16* __restrict__ t_out, int N) {
    const int wave = threadIdx.x >> 6, lane = threadIdx.x & 63;
    const int col = lane & 15, quad = lane >> 4;
    const int r0 = blockIdx.x * 64 + wave * 16;
    int arow = r0 + col; if (arow >= N) arow = N - 1;
    f16x8 a[4];
    const _Float16* hp = hh + (size_t)arow * DF + quad * 8;
#pragma unroll
    for (int kt = 0; kt < 4; kt++) a[kt] = *(const f16x8*)(hp + kt * 32);
#pragma unroll
    for (int ktype = 0; ktype < N_ETYPES; ktype++) {
        const _Float16* W = Wl + (size_t)ktype * DF * DF;
        _Float16* tk = t_out + (size_t)ktype * N * DF;
#pragma unroll
        for (int ft = 0; ft < 8; ft++) {
            f32x4 acc = {0.f, 0.f, 0.f, 0.f};
            const _Float16* wrow = W + (size_t)(ft * 16 + col) * DF + quad * 8;
#pragma unroll
            for (int kt = 0; kt < 4; kt++)
                acc = __builtin_amdgcn_mfma_f32_16x16x32_f16(
                    a[kt], *(const f16x8*)(wrow + kt * 32), acc, 0, 0, 0);
            float bias = b_lin[ktype * DF + ft * 16 + col];
#pragma unroll
            for (int i = 0; i < 4; i++) {
                int row = r0 + quad * 4 + i;
                if (row < N)
                    tk[(size_t)row * DF + ft * 16 + col] = (_Float16)(acc[i] + bias);
            }
        }
    }
}

// a[n][:] = sum over incoming edges of t[et][src][:]  -> f16
// one wave per node; 4 independent edge-row loads in flight per iteration
__global__ __launch_bounds__(256) void k_agg(
    const _Float16* __restrict__ t, const int* __restrict__ row_start,
    const int* __restrict__ csr, _Float16* __restrict__ ah, int N) {
    const int wave = threadIdx.x >> 6, lane = threadIdx.x & 63;
    const int n = blockIdx.x * 4 + wave;             // grid = N/4 exactly
    const int beg = row_start[n], end = row_start[n + 1];
    float s0 = 0.f, s1 = 0.f, s2 = 0.f, s3 = 0.f;
    float s4 = 0.f, s5 = 0.f, s6 = 0.f, s7 = 0.f;
    int e = beg;
    for (; e + 3 < end; e += 4) {
        int p0 = csr[e], p1 = csr[e + 1], p2 = csr[e + 2], p3 = csr[e + 3];
        f16x2 v0 = *(const f16x2*)(t + ((((size_t)(p0 >> 16)) * N + (p0 & 0xFFFF)) << 7) + lane * 2);
        f16x2 v1 = *(const f16x2*)(t + ((((size_t)(p1 >> 16)) * N + (p1 & 0xFFFF)) << 7) + lane * 2);
        f16x2 v2 = *(const f16x2*)(t + ((((size_t)(p2 >> 16)) * N + (p2 & 0xFFFF)) << 7) + lane * 2);
        f16x2 v3 = *(const f16x2*)(t + ((((size_t)(p3 >> 16)) * N + (p3 & 0xFFFF)) << 7) + lane * 2);
        s0 += (float)v0.x; s1 += (float)v0.y;
        s2 += (float)v1.x; s3 += (float)v1.y;
        s4 += (float)v2.x; s5 += (float)v2.y;
        s6 += (float)v3.x; s7 += (float)v3.y;
    }
    for (; e < end; e++) {
        int p0 = csr[e];
        f16x2 v0 = *(const f16x2*)(t + ((((size_t)(p0 >> 16)) * N + (p0 & 0xFFFF)) << 7) + lane * 2);
        s0 += (float)v0.x; s1 += (float)v0.y;
    }
    f16x2 o;
    o.x = (_Float16)(s0 + s2 + s4 + s6);
    o.y = (_Float16)(s1 + s3 + s5 + s7);
    *(f16x2*)(ah + ((size_t)n << 7) + lane * 2) = o;
}

// GRU: gi = a@wih.T + b_ih, gh = h@whh.T + b_hh, gates, h' -> fp32 + f16
// blockIdx.y = col-group of 32 (2 MFMA col-tiles) -> A-frags reused 2x in-wave,
// grid-level A redundancy 4x (was 8x).
__global__ __launch_bounds__(256) void k_gru(
    const _Float16* __restrict__ ah, const _Float16* __restrict__ hh,
    const _Float16* __restrict__ wih, const _Float16* __restrict__ whh,
    const float* __restrict__ b_ih, const float* __restrict__ b_hh,
    const float* h_in, float* h_out, _Float16* __restrict__ hh_next, int N) {
    const int wave = threadIdx.x >> 6, lane = threadIdx.x & 63;
    const int col = lane & 15, quad = lane >> 4;
    const int r0 = blockIdx.x * 64 + wave * 16;
    const int c0 = blockIdx.y * 32;
    int arow = r0 + col; if (arow >= N) arow = N - 1;
    f16x8 af[4], hf[4];
    const _Float16* ap = ah + (size_t)arow * DF + quad * 8;
    const _Float16* hp = hh + (size_t)arow * DF + quad * 8;
#pragma unroll
    for (int kt = 0; kt < 4; kt++) {
        af[kt] = *(const f16x8*)(ap + kt * 32);
        hf[kt] = *(const f16x8*)(hp + kt * 32);
    }
    f32x4 acc[2][6];
#pragma unroll
    for (int ct = 0; ct < 2; ct++)
#pragma unroll
        for (int g = 0; g < 6; g++) acc[ct][g] = (f32x4){0.f, 0.f, 0.f, 0.f};
#pragma unroll
    for (int ct = 0; ct < 2; ct++) {
        const _Float16* wr = wih + (size_t)(c0 + ct * 16 + col) * DF + quad * 8;
        const _Float16* wz = wr + 128 * DF;
        const _Float16* wn = wr + 256 * DF;
        const _Float16* vr = whh + (size_t)(c0 + ct * 16 + col) * DF + quad * 8;
        const _Float16* vz = vr + 128 * DF;
        const _Float16* vn = vr + 256 * DF;
#pragma unroll
        for (int kt = 0; kt < 4; kt++) {
            acc[ct][0] = __builtin_amdgcn_mfma_f32_16x16x32_f16(af[kt], *(const f16x8*)(wr + kt * 32), acc[ct][0], 0, 0, 0);
            acc[ct][1] = __builtin_amdgcn_mfma_f32_16x16x32_f16(af[kt], *(const f16x8*)(wz + kt * 32), acc[ct][1], 0, 0, 0);
            acc[ct][2] = __builtin_amdgcn_mfma_f32_16x16x32_f16(af[kt], *(const f16x8*)(wn + kt * 32), acc[ct][2], 0, 0, 0);
            acc[ct][3] = __builtin_amdgcn_mfma_f32_16x16x32_f16(hf[kt], *(const f16x8*)(vr + kt * 32), acc[ct][3], 0, 0, 0);
            acc[ct][4] = __builtin_amdgcn_mfma_f32_16x16x32_f16(hf[kt], *(const f16x8*)(vz + kt * 32), acc[ct][4], 0, 0, 0);
            acc[ct][5] = __builtin_amdgcn_mfma_f32_16x16x32_f16(hf[kt], *(const f16x8*)(vn + kt * 32), acc[ct][5], 0, 0, 0);
        }
    }
#pragma unroll
    for (int ct = 0; ct < 2; ct++) {
        const int c = c0 + ct * 16 + col;
        const float bir = b_ih[c], biz = b_ih[128 + c], bin = b_ih[256 + c];
        const float bhr = b_hh[c], bhz = b_hh[128 + c], bhn = b_hh[256 + c];
#pragma unroll
        for (int i = 0; i < 4; i++) {
            int row = r0 + quad * 4 + i;
            if (row < N) {
                float r = sigmoid_fast(acc[ct][0][i] + bir + acc[ct][3][i] + bhr);
                float z = sigmoid_fast(acc[ct][1][i] + biz + acc[ct][4][i] + bhz);
                float n = tanh_fast(acc[ct][2][i] + bin + r * (acc[ct][5][i] + bhn));
                size_t idx = (size_t)row * DF + c;
                float hprev = h_in[idx];
                float hv = (1.f - z) * n + z * hprev;
                h_out[idx] = hv;
                hh_next[idx] = (_Float16)hv;
            }
        }
    }
}

// ---------------- launch ----------------

extern "C" void kernel_launch(void* const* d_in, const int* in_sizes, int n_in,
                              void* d_out, int out_size, void* d_ws, size_t ws_size,
                              hipStream_t stream) {
    const float* h0    = (const float*)d_in[0];
    const int*   src   = (const int*)d_in[1];
    const int*   dst   = (const int*)d_in[2];
    const int*   ety   = (const int*)d_in[3];
    const float* W_lin = (const float*)d_in[4];
    const float* b_lin = (const float*)d_in[5];
    const float* w_ih  = (const float*)d_in[6];
    const float* w_hh  = (const float*)d_in[7];
    const float* b_ih  = (const float*)d_in[8];
    const float* b_hh  = (const float*)d_in[9];
    float* hout = (float*)d_out;

    char* p = (char*)d_ws;
    auto alloc = [&](size_t bytes) -> char* {
        char* r = p;
        p += (bytes + 255) & ~(size_t)255;
        return r;
    };
    _Float16* h_half_a = (_Float16*)alloc((size_t)N_NODES * DF * 2);
    _Float16* h_half_b = (_Float16*)alloc((size_t)N_NODES * DF * 2);
    _Float16* a_half   = (_Float16*)alloc((size_t)N_NODES * DF * 2);
    _Float16* t_half   = (_Float16*)alloc((size_t)N_ETYPES * N_NODES * DF * 2);
    _Float16* Wl_h     = (_Float16*)alloc((size_t)N_ETYPES * DF * DF * 2);
    _Float16* wih_h    = (_Float16*)alloc((size_t)3 * DF * DF * 2);
    _Float16* whh_h    = (_Float16*)alloc((size_t)3 * DF * DF * 2);
    int* deg       = (int*)alloc((size_t)N_NODES * 4);
    int* row_start = (int*)alloc((size_t)(N_NODES + 1) * 4);
    int* cursor    = (int*)alloc((size_t)N_NODES * 4);
    int* csr       = (int*)alloc((size_t)N_EDGES * 4);
    int* part      = (int*)alloc((size_t)SCAN_NB * 4);

    hipMemsetAsync(deg, 0, (size_t)N_NODES * 4, stream);
    k_cvt_w<<<256, 256, 0, stream>>>(W_lin, w_ih, w_hh, Wl_h, wih_h, whh_h);
    k_cvt_h<<<(N_NODES * DF / 4 + 255) / 256, 256, 0, stream>>>(h0, h_half_a, N_NODES * DF / 4);
    k_hist<<<(N_EDGES + 255) / 256, 256, 0, stream>>>(dst, deg, N_EDGES);
    k_part<<<SCAN_NB, 256, 0, stream>>>(deg, part, N_NODES);
    k_scan1<<<1, 256, 0, stream>>>(part, SCAN_NB);
    k_row<<<SCAN_NB, 256, 0, stream>>>(deg, part, row_start, cursor, N_NODES);
    k_fill<<<(N_EDGES + 255) / 256, 256, 0, stream>>>(src, dst, ety, cursor, csr, N_EDGES);

    _Float16* hc = h_half_a;
    _Float16* hn = h_half_b;
    const int nb = (N_NODES + 63) / 64;              // 782
    for (int s = 0; s < N_STEPS; s++) {
        k_lin<<<nb, 256, 0, stream>>>(hc, Wl_h, b_lin, t_half, N_NODES);
        k_agg<<<N_NODES / 4, 256, 0, stream>>>(t_half, row_start, csr, a_half, N_NODES);
        const float* hin = (s == 0) ? h0 : hout;
        k_gru<<<dim3(nb, 4), 256, 0, stream>>>(a_half, hc, wih_h, whh_h, b_ih, b_hh,
                                               hin, hout, hn, N_NODES);
        _Float16* tmp = hc; hc = hn; hn = tmp;
    }
}